// Round 4
// baseline (195.310 us; speedup 1.0000x reference)
//
#include <hip/hip_runtime.h>
#include <stdint.h>

// Problem constants (match reference)
#define B_ 4096
#define C_ 200
#define P_ 32
#define F_ 512
#define N_ (C_*P_)        // 6400 prototypes total
#define ALPHA_ 5.0
#define EPS_ 1e-8

typedef unsigned char u8;
typedef __attribute__((ext_vector_type(4))) float floatx4;  // MFMA C/D frag

union frag8 { int2 v; long l; };   // 8 fp8 elements = 2 VGPRs

// ---------- prep: fp32 -> fp8 e4m3 rows, plus p2 for cluster rows ----------
// One wave per row. Rows [0,B) = outputs -> A8. Rows [B, B+N) = clusters -> B8 (+p2).
__global__ void prep_kernel(const float* __restrict__ outputs, const float* __restrict__ clusters,
                            u8* __restrict__ A8, u8* __restrict__ B8, float* __restrict__ p2) {
    int row  = blockIdx.x * 4 + (threadIdx.x >> 6);
    int lane = threadIdx.x & 63;
    const float* src; u8* dst; bool isB;
    if (row < B_) { src = outputs + (size_t)row * F_;        dst = A8 + (size_t)row * F_;        isB = false; }
    else          { src = clusters + (size_t)(row - B_) * F_; dst = B8 + (size_t)(row - B_) * F_; isB = true; }
    float4 v0 = ((const float4*)src)[lane * 2];
    float4 v1 = ((const float4*)src)[lane * 2 + 1];
    int lo = __builtin_amdgcn_cvt_pk_fp8_f32(v0.x, v0.y, 0, false);
    lo     = __builtin_amdgcn_cvt_pk_fp8_f32(v0.z, v0.w, lo, true);
    int hi = __builtin_amdgcn_cvt_pk_fp8_f32(v1.x, v1.y, 0, false);
    hi     = __builtin_amdgcn_cvt_pk_fp8_f32(v1.z, v1.w, hi, true);
    ((int2*)dst)[lane] = make_int2(lo, hi);
    if (isB) {
        float s = v0.x*v0.x + v0.y*v0.y + v0.z*v0.z + v0.w*v0.w
                + v1.x*v1.x + v1.y*v1.y + v1.z*v1.z + v1.w*v1.w;
#pragma unroll
        for (int m = 32; m >= 1; m >>= 1) s += __shfl_xor(s, m);
        if (lane == 0) p2[row - B_] = s;
    }
}

// ---------- score kernel: barrier-free fp8 MFMA GEMM, frags streamed global->VGPR ----------
// No LDS, no __syncthreads in the K-loop: loads double-buffered in registers,
// compiler emits partial vmcnt waits (AITER-style), latency hidden by ILP + 3 waves/SIMD.
#define BM 128
#define BN 128

__global__ __launch_bounds__(256, 3)
void score_kernel(const u8* __restrict__ A8, const u8* __restrict__ B8,
                  const float* __restrict__ p2,
                  float* __restrict__ min_d, int* __restrict__ min_idx) {
    const int tid  = threadIdx.x;
    const int lane = tid & 63;
    const int w    = tid >> 6;          // wave 0..3 (2x2 wave grid, 64x64 per wave)
    const int wm   = w >> 1, wn = w & 1;
    const int bx   = blockIdx.x;        // n-tile 0..49
    const int by   = blockIdx.y;        // m-tile 0..31
    const int m0   = by * BM, n0 = bx * BN;
    const int mrow = lane & 15;         // M/N index within a 16x16 MFMA tile
    const int quad = lane >> 4;         // 0..3; A/B frag: k = quad*8 + j (8 contiguous fp8)

    // Per-lane base pointers (k-contiguous rows, pitch F_=512 bytes in fp8)
    const u8* ap = A8 + (size_t)(m0 + wm * 64 + mrow) * F_ + quad * 8;
    const u8* bp = B8 + (size_t)(n0 + wn * 64 + mrow) * F_ + quad * 8;

    floatx4 zf = {0.f, 0.f, 0.f, 0.f};
    floatx4 acc[4][4];
#pragma unroll
    for (int i = 0; i < 4; ++i)
#pragma unroll
        for (int j = 0; j < 4; ++j) acc[i][j] = zf;

    frag8 af[2][4], bf[2][4];
#pragma unroll
    for (int t = 0; t < 4; ++t) {
        af[0][t].v = *(const int2*)(ap + t * 16 * F_);
        bf[0][t].v = *(const int2*)(bp + t * 16 * F_);
    }

#pragma unroll 2
    for (int ks = 0; ks < 16; ++ks) {
        const int cur = ks & 1, nxt = cur ^ 1;
        if (ks < 15) {
            const int k0 = (ks + 1) * 32;
#pragma unroll
            for (int t = 0; t < 4; ++t) {
                af[nxt][t].v = *(const int2*)(ap + t * 16 * F_ + k0);
                bf[nxt][t].v = *(const int2*)(bp + t * 16 * F_ + k0);
            }
        }
#pragma unroll
        for (int mt = 0; mt < 4; ++mt)
#pragma unroll
            for (int nt = 0; nt < 4; ++nt)
                acc[mt][nt] = __builtin_amdgcn_mfma_f32_16x16x32_fp8_fp8(
                    af[cur][mt].l, bf[cur][nt].l, acc[mt][nt], 0, 0, 0);
    }

    // Epilogue: score = p2[n] - 2*xp (x2 dropped: constant per row b, argmins unchanged).
    // C/D layout: col = lane&15, row = quad*4 + reg. Each wave: 64 rows x 2 classes.
    float pg[4];
#pragma unroll
    for (int nt = 0; nt < 4; ++nt) pg[nt] = p2[n0 + wn * 64 + nt * 16 + mrow];

#pragma unroll
    for (int ch = 0; ch < 2; ++ch) {
        const int cls = bx * 4 + wn * 2 + ch;
#pragma unroll
        for (int mt = 0; mt < 4; ++mt)
#pragma unroll
            for (int reg = 0; reg < 4; ++reg) {
                float v0 = pg[ch * 2]     - 2.0f * acc[mt][ch * 2][reg];     // p = mrow
                float v1 = pg[ch * 2 + 1] - 2.0f * acc[mt][ch * 2 + 1][reg]; // p = 16+mrow
                float v; int pi;
                if (v1 < v0) { v = v1; pi = 16 + mrow; } else { v = v0; pi = mrow; }
#pragma unroll
                for (int m = 8; m >= 1; m >>= 1) {
                    float ov = __shfl_xor(v, m);
                    int   oi = __shfl_xor(pi, m);
                    if (ov < v || (ov == v && oi < pi)) { v = ov; pi = oi; }
                }
                if (mrow == 0) {
                    int grow = m0 + wm * 64 + mt * 16 + quad * 4 + reg;
                    min_d[grow * C_ + cls]   = v;
                    min_idx[grow * C_ + cls] = pi;
                }
            }
    }
}

// ---------- per-sample selection + exact fp32 distances (no atomics) ----------
__global__ void select_kernel(const float* __restrict__ X, const float* __restrict__ clusters,
                              const int* __restrict__ tgt, const float* __restrict__ min_d,
                              const int* __restrict__ min_idx,
                              float* __restrict__ stw, float* __restrict__ sww) {
    int b    = blockIdx.x * 4 + (threadIdx.x >> 6);
    int lane = threadIdx.x & 63;
    int tc   = tgt[b];

    float bv = 3.4e38f; int bc = 1 << 30;
    for (int c = lane; c < C_; c += 64) {
        float v = min_d[b * C_ + c];
        if (c != tc && (v < bv || (v == bv && c < bc))) { bv = v; bc = c; }
    }
#pragma unroll
    for (int m = 32; m >= 1; m >>= 1) {
        float ov = __shfl_xor(bv, m);
        int   oc = __shfl_xor(bc, m);
        if (ov < bv || (ov == bv && oc < bc)) { bv = ov; bc = oc; }
    }
    int ap = min_idx[b * C_ + tc];   // best proto in target class
    int wp = min_idx[b * C_ + bc];   // best proto in nearest wrong class

    const float4* xb = (const float4*)(X + (size_t)b * F_);
    const float4* pa = (const float4*)(clusters + ((size_t)tc * P_ + ap) * F_);
    const float4* pw = (const float4*)(clusters + ((size_t)bc * P_ + wp) * F_);
    float st = 0.f, sw = 0.f;
#pragma unroll
    for (int i = 0; i < 2; ++i) {
        float4 x = xb[lane + i * 64], a = pa[lane + i * 64], ww = pw[lane + i * 64];
        float dx = x.x - a.x, dy = x.y - a.y, dz = x.z - a.z, dw = x.w - a.w;
        st += dx*dx + dy*dy + dz*dz + dw*dw;
        dx = x.x - ww.x; dy = x.y - ww.y; dz = x.z - ww.z; dw = x.w - ww.w;
        sw += dx*dx + dy*dy + dz*dz + dw*dw;
    }
#pragma unroll
    for (int m = 32; m >= 1; m >>= 1) { st += __shfl_xor(st, m); sw += __shfl_xor(sw, m); }
    if (lane == 0) { stw[b] = st; sww[b] = sw; }
}

// Single-block reduction of 2x4096 floats + final loss
__global__ __launch_bounds__(1024)
void finalize_kernel(const float* __restrict__ stw, const float* __restrict__ sww,
                     float* __restrict__ out) {
    __shared__ float r1[16], r2[16];
    int tid = threadIdx.x;
    float s1 = 0.f, s2 = 0.f;
#pragma unroll
    for (int i = 0; i < 4; ++i) {
        s1 += stw[tid + i * 1024];
        s2 += sww[tid + i * 1024];
    }
#pragma unroll
    for (int m = 32; m >= 1; m >>= 1) { s1 += __shfl_xor(s1, m); s2 += __shfl_xor(s2, m); }
    if ((tid & 63) == 0) { r1[tid >> 6] = s1; r2[tid >> 6] = s2; }
    __syncthreads();
    if (tid == 0) {
        double t1 = 0.0, t2 = 0.0;
#pragma unroll
        for (int i = 0; i < 16; ++i) { t1 += (double)r1[i]; t2 += (double)r2[i]; }
        double denom = (double)B_ * (double)F_;
        double tl  = t1 / denom;
        double ntl = t2 / denom;
        out[0] = (float)((1.0 - ALPHA_) * tl + ALPHA_ / (ntl + EPS_));
    }
}

// ---------- launch ----------
extern "C" void kernel_launch(void* const* d_in, const int* in_sizes, int n_in,
                              void* d_out, int out_size, void* d_ws, size_t ws_size,
                              hipStream_t stream) {
    const float* outputs  = (const float*)d_in[0];
    const float* clusters = (const float*)d_in[1];
    const int*   tgt      = (const int*)d_in[2];
    float* out = (float*)d_out;

    char* ws = (char*)d_ws;
    // workspace layout (16B-aligned), total 11,953,152 bytes
    u8*     A8      = (u8*)(ws);                     // 4096*512    = 2,097,152
    u8*     B8      = (u8*)(ws + 2097152);           // 6400*512    = 3,276,800
    float*  p2      = (float*)(ws + 5373952);        // 6400*4      =    25,600
    float*  min_d   = (float*)(ws + 5399552);        // 4096*200*4  = 3,276,800
    int*    min_idx = (int*)(ws + 8676352);          // 4096*200*4  = 3,276,800
    // per-sample partials: reuse the A8 region (dead after score_kernel)
    float*  stw     = (float*)(ws);                  // 4096*4 = 16 KB
    float*  sww     = (float*)(ws + 16384);          // 4096*4 = 16 KB

    prep_kernel<<<(B_ + N_) / 4, 256, 0, stream>>>(outputs, clusters, A8, B8, p2);   // 2624 blocks
    score_kernel<<<dim3(N_ / BN, B_ / BM), 256, 0, stream>>>(A8, B8, p2, min_d, min_idx);
    select_kernel<<<B_ / 4, 256, 0, stream>>>(outputs, clusters, tgt, min_d, min_idx, stw, sww);
    finalize_kernel<<<1, 1024, 0, stream>>>(stw, sww, out);
}

// Round 5
// 148.074 us; speedup vs baseline: 1.3190x; 1.3190x over previous
//
#include <hip/hip_runtime.h>
#include <stdint.h>

// Problem constants (match reference)
#define B_ 4096
#define C_ 200
#define P_ 32
#define F_ 512
#define N_ (C_*P_)        // 6400 prototypes total
#define ALPHA_ 5.0
#define EPS_ 1e-8

typedef unsigned char u8;
typedef __attribute__((ext_vector_type(4))) float floatx4;  // MFMA C/D frag

union frag16 { int4 v; long l[2]; };   // 16 fp8 = two MFMA k-slices (virtual-K)

// ---------- prep: fp32 -> fp8 e4m3 in MFMA-native packed layout ----------
// Packed layout (per matrix): row-tile tm (16 rows), k-chunk kc (64 features),
// quad q (16 features), r = row&15. 16-B unit holds features [kc*64+q*16, +16)
// of row tm*16+r at byte offset (tm*8+kc)*1024 + (q*16+r)*16.
// => score-kernel frag load for (tile, kc) is base + lane*16: fully coalesced 1KB.
// One thread per 16-B chunk. Threads [0,131072) = A (outputs); rest = B (clusters)+p2.
// Block 512 is the exact A/B boundary (131072/256), so waves are never mixed.
__global__ void prep_kernel(const float* __restrict__ outputs, const float* __restrict__ clusters,
                            u8* __restrict__ At, u8* __restrict__ Bt, float* __restrict__ p2) {
    int t = blockIdx.x * 256 + threadIdx.x;
    const float* src; u8* dst; int row, cid; bool isB;
    if (t < B_ * 32) { row = t >> 5;  cid = t & 31;  src = outputs;  dst = At; isB = false; }
    else { t -= B_ * 32; row = t >> 5; cid = t & 31; src = clusters; dst = Bt; isB = true; }
    const int kc = cid >> 2, q = cid & 3, tm = row >> 4, r = row & 15;

    const float4* s = (const float4*)(src + (size_t)row * F_ + cid * 16);
    float4 v0 = s[0], v1 = s[1], v2 = s[2], v3 = s[3];
    int4 o;
    o.x = __builtin_amdgcn_cvt_pk_fp8_f32(v0.x, v0.y, 0, false);
    o.x = __builtin_amdgcn_cvt_pk_fp8_f32(v0.z, v0.w, o.x, true);
    o.y = __builtin_amdgcn_cvt_pk_fp8_f32(v1.x, v1.y, 0, false);
    o.y = __builtin_amdgcn_cvt_pk_fp8_f32(v1.z, v1.w, o.y, true);
    o.z = __builtin_amdgcn_cvt_pk_fp8_f32(v2.x, v2.y, 0, false);
    o.z = __builtin_amdgcn_cvt_pk_fp8_f32(v2.z, v2.w, o.z, true);
    o.w = __builtin_amdgcn_cvt_pk_fp8_f32(v3.x, v3.y, 0, false);
    o.w = __builtin_amdgcn_cvt_pk_fp8_f32(v3.z, v3.w, o.w, true);
    *(int4*)(dst + ((size_t)(tm * 8 + kc) << 10) + (q * 16 + r) * 16) = o;

    if (isB) {
        // p2: each row's 32 chunks sit on 32 consecutive lanes (aligned 32-groups)
        float ss = v0.x*v0.x + v0.y*v0.y + v0.z*v0.z + v0.w*v0.w
                 + v1.x*v1.x + v1.y*v1.y + v1.z*v1.z + v1.w*v1.w
                 + v2.x*v2.x + v2.y*v2.y + v2.z*v2.z + v2.w*v2.w
                 + v3.x*v3.x + v3.y*v3.y + v3.z*v3.z + v3.w*v3.w;
#pragma unroll
        for (int m = 16; m >= 1; m >>= 1) ss += __shfl_xor(ss, m);
        if (cid == 0) p2[row] = ss;
    }
}

// ---------- score kernel: barrier-free fp8 MFMA GEMM from packed operands ----------
// No LDS, no __syncthreads: coalesced 1KB frag loads (base + lane*16), register
// double-buffered over 8 K-chunks of 64. Virtual-K: both A and B feed features in
// the same permuted order, so dot products (and thus scores) are exact.
#define BM 128
#define BN 128

__global__ __launch_bounds__(256, 3)
void score_kernel(const u8* __restrict__ At, const u8* __restrict__ Bt,
                  const float* __restrict__ p2,
                  float* __restrict__ min_d, int* __restrict__ min_idx) {
    const int tid  = threadIdx.x;
    const int lane = tid & 63;
    const int w    = tid >> 6;          // wave 0..3 (2x2 wave grid, 64x64 per wave)
    const int wm   = w >> 1, wn = w & 1;
    const int bx   = blockIdx.x;        // n-tile 0..49
    const int by   = blockIdx.y;        // m-tile 0..31
    const int m0   = by * BM, n0 = bx * BN;
    const int mrow = lane & 15;
    const int quad = lane >> 4;

    // per-(wave,mt/nt) packed tile bases; chunk kc advances by 1024 B
    const u8* ap = At + ((size_t)((m0 >> 4) + wm * 4) << 13) + lane * 16;  // tile stride 8KB
    const u8* bp = Bt + ((size_t)((n0 >> 4) + wn * 4) << 13) + lane * 16;

    floatx4 zf = {0.f, 0.f, 0.f, 0.f};
    floatx4 acc[4][4];
#pragma unroll
    for (int i = 0; i < 4; ++i)
#pragma unroll
        for (int j = 0; j < 4; ++j) acc[i][j] = zf;

    frag16 a[2][4], b[2][4];
#pragma unroll
    for (int t = 0; t < 4; ++t) {
        a[0][t].v = *(const int4*)(ap + t * 8192);
        b[0][t].v = *(const int4*)(bp + t * 8192);
    }

#pragma unroll
    for (int kc = 0; kc < 8; ++kc) {
        const int cur = kc & 1, nxt = cur ^ 1;
        if (kc < 7) {
            const int off = (kc + 1) << 10;
#pragma unroll
            for (int t = 0; t < 4; ++t) {
                a[nxt][t].v = *(const int4*)(ap + t * 8192 + off);
                b[nxt][t].v = *(const int4*)(bp + t * 8192 + off);
            }
        }
#pragma unroll
        for (int s = 0; s < 2; ++s)
#pragma unroll
            for (int mt = 0; mt < 4; ++mt)
#pragma unroll
                for (int nt = 0; nt < 4; ++nt)
                    acc[mt][nt] = __builtin_amdgcn_mfma_f32_16x16x32_fp8_fp8(
                        a[cur][mt].l[s], b[cur][nt].l[s], acc[mt][nt], 0, 0, 0);
    }

    // Epilogue: score = p2[n] - 2*xp (x2 dropped: constant per row b, argmins unchanged).
    // C/D layout: col = lane&15, row = quad*4 + reg. Each wave: 64 rows x 2 classes.
    float pg[4];
#pragma unroll
    for (int nt = 0; nt < 4; ++nt) pg[nt] = p2[n0 + wn * 64 + nt * 16 + mrow];

#pragma unroll
    for (int ch = 0; ch < 2; ++ch) {
        const int cls = bx * 4 + wn * 2 + ch;
#pragma unroll
        for (int mt = 0; mt < 4; ++mt)
#pragma unroll
            for (int reg = 0; reg < 4; ++reg) {
                float v0 = pg[ch * 2]     - 2.0f * acc[mt][ch * 2][reg];     // p = mrow
                float v1 = pg[ch * 2 + 1] - 2.0f * acc[mt][ch * 2 + 1][reg]; // p = 16+mrow
                float v; int pi;
                if (v1 < v0) { v = v1; pi = 16 + mrow; } else { v = v0; pi = mrow; }
#pragma unroll
                for (int m = 8; m >= 1; m >>= 1) {
                    float ov = __shfl_xor(v, m);
                    int   oi = __shfl_xor(pi, m);
                    if (ov < v || (ov == v && oi < pi)) { v = ov; pi = oi; }
                }
                if (mrow == 0) {
                    int grow = m0 + wm * 64 + mt * 16 + quad * 4 + reg;
                    min_d[grow * C_ + cls]   = v;
                    min_idx[grow * C_ + cls] = pi;
                }
            }
    }
}

// ---------- per-sample selection + exact fp32 distances (no atomics) ----------
__global__ void select_kernel(const float* __restrict__ X, const float* __restrict__ clusters,
                              const int* __restrict__ tgt, const float* __restrict__ min_d,
                              const int* __restrict__ min_idx,
                              float* __restrict__ stw, float* __restrict__ sww) {
    int b    = blockIdx.x * 4 + (threadIdx.x >> 6);
    int lane = threadIdx.x & 63;
    int tc   = tgt[b];

    float bv = 3.4e38f; int bc = 1 << 30;
    for (int c = lane; c < C_; c += 64) {
        float v = min_d[b * C_ + c];
        if (c != tc && (v < bv || (v == bv && c < bc))) { bv = v; bc = c; }
    }
#pragma unroll
    for (int m = 32; m >= 1; m >>= 1) {
        float ov = __shfl_xor(bv, m);
        int   oc = __shfl_xor(bc, m);
        if (ov < bv || (ov == bv && oc < bc)) { bv = ov; bc = oc; }
    }
    int ap = min_idx[b * C_ + tc];   // best proto in target class
    int wp = min_idx[b * C_ + bc];   // best proto in nearest wrong class

    const float4* xb = (const float4*)(X + (size_t)b * F_);
    const float4* pa = (const float4*)(clusters + ((size_t)tc * P_ + ap) * F_);
    const float4* pw = (const float4*)(clusters + ((size_t)bc * P_ + wp) * F_);
    float st = 0.f, sw = 0.f;
#pragma unroll
    for (int i = 0; i < 2; ++i) {
        float4 x = xb[lane + i * 64], a = pa[lane + i * 64], ww = pw[lane + i * 64];
        float dx = x.x - a.x, dy = x.y - a.y, dz = x.z - a.z, dw = x.w - a.w;
        st += dx*dx + dy*dy + dz*dz + dw*dw;
        dx = x.x - ww.x; dy = x.y - ww.y; dz = x.z - ww.z; dw = x.w - ww.w;
        sw += dx*dx + dy*dy + dz*dz + dw*dw;
    }
#pragma unroll
    for (int m = 32; m >= 1; m >>= 1) { st += __shfl_xor(st, m); sw += __shfl_xor(sw, m); }
    if (lane == 0) { stw[b] = st; sww[b] = sw; }
}

// Single-block reduction of 2x4096 floats + final loss
__global__ __launch_bounds__(1024)
void finalize_kernel(const float* __restrict__ stw, const float* __restrict__ sww,
                     float* __restrict__ out) {
    __shared__ float r1[16], r2[16];
    int tid = threadIdx.x;
    float s1 = 0.f, s2 = 0.f;
#pragma unroll
    for (int i = 0; i < 4; ++i) {
        s1 += stw[tid + i * 1024];
        s2 += sww[tid + i * 1024];
    }
#pragma unroll
    for (int m = 32; m >= 1; m >>= 1) { s1 += __shfl_xor(s1, m); s2 += __shfl_xor(s2, m); }
    if ((tid & 63) == 0) { r1[tid >> 6] = s1; r2[tid >> 6] = s2; }
    __syncthreads();
    if (tid == 0) {
        double t1 = 0.0, t2 = 0.0;
#pragma unroll
        for (int i = 0; i < 16; ++i) { t1 += (double)r1[i]; t2 += (double)r2[i]; }
        double denom = (double)B_ * (double)F_;
        double tl  = t1 / denom;
        double ntl = t2 / denom;
        out[0] = (float)((1.0 - ALPHA_) * tl + ALPHA_ / (ntl + EPS_));
    }
}

// ---------- launch ----------
extern "C" void kernel_launch(void* const* d_in, const int* in_sizes, int n_in,
                              void* d_out, int out_size, void* d_ws, size_t ws_size,
                              hipStream_t stream) {
    const float* outputs  = (const float*)d_in[0];
    const float* clusters = (const float*)d_in[1];
    const int*   tgt      = (const int*)d_in[2];
    float* out = (float*)d_out;

    char* ws = (char*)d_ws;
    // workspace layout (16B-aligned), total 11,953,152 bytes
    u8*     At      = (u8*)(ws);                     // packed A: 256*8*1024 = 2,097,152
    u8*     Bt      = (u8*)(ws + 2097152);           // packed B: 400*8*1024 = 3,276,800
    float*  p2      = (float*)(ws + 5373952);        // 6400*4      =    25,600
    float*  min_d   = (float*)(ws + 5399552);        // 4096*200*4  = 3,276,800
    int*    min_idx = (int*)(ws + 8676352);          // 4096*200*4  = 3,276,800
    // per-sample partials: reuse the At region (dead after score_kernel)
    float*  stw     = (float*)(ws);                  // 4096*4 = 16 KB
    float*  sww     = (float*)(ws + 16384);          // 4096*4 = 16 KB

    prep_kernel<<<(B_ * 32 + N_ * 32) / 256, 256, 0, stream>>>(outputs, clusters, At, Bt, p2); // 1312 blocks
    score_kernel<<<dim3(N_ / BN, B_ / BM), 256, 0, stream>>>(At, Bt, p2, min_d, min_idx);
    select_kernel<<<B_ / 4, 256, 0, stream>>>(outputs, clusters, tgt, min_d, min_idx, stw, sww);
    finalize_kernel<<<1, 1024, 0, stream>>>(stw, sww, out);
}

// Round 6
// 125.936 us; speedup vs baseline: 1.5509x; 1.1758x over previous
//
#include <hip/hip_runtime.h>
#include <stdint.h>

// Problem constants (match reference)
#define B_ 4096
#define C_ 200
#define P_ 32
#define F_ 512
#define N_ (C_*P_)        // 6400 prototypes total
#define ALPHA_ 5.0
#define EPS_ 1e-8

typedef unsigned char u8;
typedef __attribute__((ext_vector_type(4))) float floatx4;  // MFMA C/D frag

union frag16 { int4 v; long l[2]; };   // 16 fp8 = two MFMA k-slices (virtual-K)

// ---------- prep: fp32 -> fp8 e4m3 in MFMA-native packed layout ----------
// Packed layout (per matrix): row-tile tm (16 rows), k-chunk kc (64 features),
// quad q (16 features), r = row&15. 16-B unit holds features [kc*64+q*16, +16)
// of row tm*16+r at byte offset (tm*8+kc)*1024 + (q*16+r)*16.
// => one (tm,kc) chunk is a contiguous 1KB whose lane-i 16B slot is base+i*16.
__global__ void prep_kernel(const float* __restrict__ outputs, const float* __restrict__ clusters,
                            u8* __restrict__ At, u8* __restrict__ Bt, float* __restrict__ p2) {
    int t = blockIdx.x * 256 + threadIdx.x;
    const float* src; u8* dst; int row, cid; bool isB;
    if (t < B_ * 32) { row = t >> 5;  cid = t & 31;  src = outputs;  dst = At; isB = false; }
    else { t -= B_ * 32; row = t >> 5; cid = t & 31; src = clusters; dst = Bt; isB = true; }
    const int kc = cid >> 2, q = cid & 3, tm = row >> 4, r = row & 15;

    const float4* s = (const float4*)(src + (size_t)row * F_ + cid * 16);
    float4 v0 = s[0], v1 = s[1], v2 = s[2], v3 = s[3];
    int4 o;
    o.x = __builtin_amdgcn_cvt_pk_fp8_f32(v0.x, v0.y, 0, false);
    o.x = __builtin_amdgcn_cvt_pk_fp8_f32(v0.z, v0.w, o.x, true);
    o.y = __builtin_amdgcn_cvt_pk_fp8_f32(v1.x, v1.y, 0, false);
    o.y = __builtin_amdgcn_cvt_pk_fp8_f32(v1.z, v1.w, o.y, true);
    o.z = __builtin_amdgcn_cvt_pk_fp8_f32(v2.x, v2.y, 0, false);
    o.z = __builtin_amdgcn_cvt_pk_fp8_f32(v2.z, v2.w, o.z, true);
    o.w = __builtin_amdgcn_cvt_pk_fp8_f32(v3.x, v3.y, 0, false);
    o.w = __builtin_amdgcn_cvt_pk_fp8_f32(v3.z, v3.w, o.w, true);
    *(int4*)(dst + ((size_t)(tm * 8 + kc) << 10) + (q * 16 + r) * 16) = o;

    if (isB) {
        float ss = v0.x*v0.x + v0.y*v0.y + v0.z*v0.z + v0.w*v0.w
                 + v1.x*v1.x + v1.y*v1.y + v1.z*v1.z + v1.w*v1.w
                 + v2.x*v2.x + v2.y*v2.y + v2.z*v2.z + v2.w*v2.w
                 + v3.x*v3.x + v3.y*v3.y + v3.z*v3.z + v3.w*v3.w;
#pragma unroll
        for (int m = 16; m >= 1; m >>= 1) ss += __shfl_xor(ss, m);
        if (cid == 0) p2[row] = ss;
    }
}

// ---------- score kernel: LDS double-buffered fp8 MFMA GEMM, 1-stage-ahead prefetch ----------
// Per stage (64 features): async global_load_lds prefetch of stage kc+1 issued BEFORE
// consuming stage kc, so the vmcnt(0) drain at the single per-stage barrier is pre-paid
// by ~the stage's compute time. LDS reads at lane*16 are conflict-free.
#define BM 128
#define BN 128

typedef const __attribute__((address_space(1))) unsigned int gu32_t;
typedef __attribute__((address_space(3))) unsigned int lu32_t;

__device__ __forceinline__ void gld16(const u8* g, u8* l) {
    // per-lane global src (16B each); LDS dest = wave-uniform base + lane*16
    __builtin_amdgcn_global_load_lds((gu32_t*)g, (lu32_t*)l, 16, 0, 0);
}

__global__ __launch_bounds__(256, 4)
void score_kernel(const u8* __restrict__ At, const u8* __restrict__ Bt,
                  const float* __restrict__ p2,
                  float* __restrict__ min_d, int* __restrict__ min_idx) {
    __shared__ __align__(16) u8 lds[2][16384];   // [buf][ A: 8 tiles x 1KB | B: 8 tiles x 1KB ]

    const int tid  = threadIdx.x;
    const int lane = tid & 63;
    const int w    = tid >> 6;          // wave 0..3 (2x2 wave grid, 64x64 per wave)
    const int wm   = w >> 1, wn = w & 1;
    const int bx   = blockIdx.x;        // n-tile 0..49
    const int by   = blockIdx.y;        // m-tile 0..31
    const int m0   = by * BM, n0 = bx * BN;
    const int mrow = lane & 15;
    const int quad = lane >> 4;
    const int l16  = lane * 16;

    const u8* ag = At + ((size_t)(by * 8) << 13);   // 8 row-tiles x 8KB each
    const u8* bg = Bt + ((size_t)(bx * 8) << 13);

    floatx4 zf = {0.f, 0.f, 0.f, 0.f};
    floatx4 acc[4][4];
#pragma unroll
    for (int i = 0; i < 4; ++i)
#pragma unroll
        for (int j = 0; j < 4; ++j) acc[i][j] = zf;

    // prologue: prefetch stage 0 into buf 0 (wave w loads A tiles {w,w+4}, B tiles {w,w+4})
    gld16(ag + ((w * 8) << 10) + l16,           lds[0] + w * 1024);
    gld16(ag + (((w + 4) * 8) << 10) + l16,     lds[0] + (w + 4) * 1024);
    gld16(bg + ((w * 8) << 10) + l16,           lds[0] + 8192 + w * 1024);
    gld16(bg + (((w + 4) * 8) << 10) + l16,     lds[0] + 8192 + (w + 4) * 1024);
    __syncthreads();

#pragma unroll
    for (int kc = 0; kc < 8; ++kc) {
        const int cur = kc & 1;
        if (kc < 7) {
            const int nb = cur ^ 1, kn = kc + 1;
            gld16(ag + ((w * 8 + kn) << 10) + l16,         lds[nb] + w * 1024);
            gld16(ag + (((w + 4) * 8 + kn) << 10) + l16,   lds[nb] + (w + 4) * 1024);
            gld16(bg + ((w * 8 + kn) << 10) + l16,         lds[nb] + 8192 + w * 1024);
            gld16(bg + (((w + 4) * 8 + kn) << 10) + l16,   lds[nb] + 8192 + (w + 4) * 1024);
        }
        frag16 a[4], b[4];
#pragma unroll
        for (int t = 0; t < 4; ++t) {
            a[t].v = *(const int4*)(lds[cur] + (wm * 4 + t) * 1024 + l16);
            b[t].v = *(const int4*)(lds[cur] + 8192 + (wn * 4 + t) * 1024 + l16);
        }
#pragma unroll
        for (int s = 0; s < 2; ++s)
#pragma unroll
            for (int mt = 0; mt < 4; ++mt)
#pragma unroll
                for (int nt = 0; nt < 4; ++nt)
                    acc[mt][nt] = __builtin_amdgcn_mfma_f32_16x16x32_fp8_fp8(
                        a[mt].l[s], b[nt].l[s], acc[mt][nt], 0, 0, 0);
        __syncthreads();   // drains prefetch vmcnt + guards buf reuse (1 barrier/stage)
    }

    // Epilogue: score = p2[n] - 2*xp (x2 dropped: constant per row b, argmins unchanged).
    // C/D layout: col = lane&15, row = quad*4 + reg. Each wave: 64 rows x 2 classes.
    float pg[4];
#pragma unroll
    for (int nt = 0; nt < 4; ++nt) pg[nt] = p2[n0 + wn * 64 + nt * 16 + mrow];

#pragma unroll
    for (int ch = 0; ch < 2; ++ch) {
        const int cls = bx * 4 + wn * 2 + ch;
#pragma unroll
        for (int mt = 0; mt < 4; ++mt)
#pragma unroll
            for (int reg = 0; reg < 4; ++reg) {
                float v0 = pg[ch * 2]     - 2.0f * acc[mt][ch * 2][reg];     // p = mrow
                float v1 = pg[ch * 2 + 1] - 2.0f * acc[mt][ch * 2 + 1][reg]; // p = 16+mrow
                float v; int pi;
                if (v1 < v0) { v = v1; pi = 16 + mrow; } else { v = v0; pi = mrow; }
#pragma unroll
                for (int m = 8; m >= 1; m >>= 1) {
                    float ov = __shfl_xor(v, m);
                    int   oi = __shfl_xor(pi, m);
                    if (ov < v || (ov == v && oi < pi)) { v = ov; pi = oi; }
                }
                if (mrow == 0) {
                    int grow = m0 + wm * 64 + mt * 16 + quad * 4 + reg;
                    min_d[grow * C_ + cls]   = v;
                    min_idx[grow * C_ + cls] = pi;
                }
            }
    }
}

// ---------- per-sample selection + exact fp32 distances (no atomics) ----------
__global__ void select_kernel(const float* __restrict__ X, const float* __restrict__ clusters,
                              const int* __restrict__ tgt, const float* __restrict__ min_d,
                              const int* __restrict__ min_idx,
                              float* __restrict__ stw, float* __restrict__ sww) {
    int b    = blockIdx.x * 4 + (threadIdx.x >> 6);
    int lane = threadIdx.x & 63;
    int tc   = tgt[b];

    float bv = 3.4e38f; int bc = 1 << 30;
    for (int c = lane; c < C_; c += 64) {
        float v = min_d[b * C_ + c];
        if (c != tc && (v < bv || (v == bv && c < bc))) { bv = v; bc = c; }
    }
#pragma unroll
    for (int m = 32; m >= 1; m >>= 1) {
        float ov = __shfl_xor(bv, m);
        int   oc = __shfl_xor(bc, m);
        if (ov < bv || (ov == bv && oc < bc)) { bv = ov; bc = oc; }
    }
    int ap = min_idx[b * C_ + tc];   // best proto in target class
    int wp = min_idx[b * C_ + bc];   // best proto in nearest wrong class

    const float4* xb = (const float4*)(X + (size_t)b * F_);
    const float4* pa = (const float4*)(clusters + ((size_t)tc * P_ + ap) * F_);
    const float4* pw = (const float4*)(clusters + ((size_t)bc * P_ + wp) * F_);
    float st = 0.f, sw = 0.f;
#pragma unroll
    for (int i = 0; i < 2; ++i) {
        float4 x = xb[lane + i * 64], a = pa[lane + i * 64], ww = pw[lane + i * 64];
        float dx = x.x - a.x, dy = x.y - a.y, dz = x.z - a.z, dw = x.w - a.w;
        st += dx*dx + dy*dy + dz*dz + dw*dw;
        dx = x.x - ww.x; dy = x.y - ww.y; dz = x.z - ww.z; dw = x.w - ww.w;
        sw += dx*dx + dy*dy + dz*dz + dw*dw;
    }
#pragma unroll
    for (int m = 32; m >= 1; m >>= 1) { st += __shfl_xor(st, m); sw += __shfl_xor(sw, m); }
    if (lane == 0) { stw[b] = st; sww[b] = sw; }
}

// Single-block reduction of 2x4096 floats + final loss
__global__ __launch_bounds__(1024)
void finalize_kernel(const float* __restrict__ stw, const float* __restrict__ sww,
                     float* __restrict__ out) {
    __shared__ float r1[16], r2[16];
    int tid = threadIdx.x;
    float s1 = 0.f, s2 = 0.f;
#pragma unroll
    for (int i = 0; i < 4; ++i) {
        s1 += stw[tid + i * 1024];
        s2 += sww[tid + i * 1024];
    }
#pragma unroll
    for (int m = 32; m >= 1; m >>= 1) { s1 += __shfl_xor(s1, m); s2 += __shfl_xor(s2, m); }
    if ((tid & 63) == 0) { r1[tid >> 6] = s1; r2[tid >> 6] = s2; }
    __syncthreads();
    if (tid == 0) {
        double t1 = 0.0, t2 = 0.0;
#pragma unroll
        for (int i = 0; i < 16; ++i) { t1 += (double)r1[i]; t2 += (double)r2[i]; }
        double denom = (double)B_ * (double)F_;
        double tl  = t1 / denom;
        double ntl = t2 / denom;
        out[0] = (float)((1.0 - ALPHA_) * tl + ALPHA_ / (ntl + EPS_));
    }
}

// ---------- launch ----------
extern "C" void kernel_launch(void* const* d_in, const int* in_sizes, int n_in,
                              void* d_out, int out_size, void* d_ws, size_t ws_size,
                              hipStream_t stream) {
    const float* outputs  = (const float*)d_in[0];
    const float* clusters = (const float*)d_in[1];
    const int*   tgt      = (const int*)d_in[2];
    float* out = (float*)d_out;

    char* ws = (char*)d_ws;
    // workspace layout (16B-aligned), total 11,953,152 bytes
    u8*     At      = (u8*)(ws);                     // packed A: 256*8*1024 = 2,097,152
    u8*     Bt      = (u8*)(ws + 2097152);           // packed B: 400*8*1024 = 3,276,800
    float*  p2      = (float*)(ws + 5373952);        // 6400*4      =    25,600
    float*  min_d   = (float*)(ws + 5399552);        // 4096*200*4  = 3,276,800
    int*    min_idx = (int*)(ws + 8676352);          // 4096*200*4  = 3,276,800
    // per-sample partials: reuse the At region (dead after score_kernel)
    float*  stw     = (float*)(ws);                  // 4096*4 = 16 KB
    float*  sww     = (float*)(ws + 16384);          // 4096*4 = 16 KB

    prep_kernel<<<(B_ * 32 + N_ * 32) / 256, 256, 0, stream>>>(outputs, clusters, At, Bt, p2); // 1312 blocks
    score_kernel<<<dim3(N_ / BN, B_ / BM), 256, 0, stream>>>(At, Bt, p2, min_d, min_idx);
    select_kernel<<<B_ / 4, 256, 0, stream>>>(outputs, clusters, tgt, min_d, min_idx, stw, sww);
    finalize_kernel<<<1, 1024, 0, stream>>>(stw, sww, out);
}